// Round 3
// baseline (29.287 us; speedup 1.0000x reference)
//
#include <hip/hip_runtime.h>
#include <hip/hip_bf16.h>

// CP tensorized embedding gather via MFMA, transposed-D for wide stores:
// out[t, e] = sum_r w[t,r] * B[r,e]
//   w[t,r] = U0[a,r]*U1[b,r]*U2[c,r], idx=x[t], a=idx/5000, b=(idx/50)%100, c=idx%50
//   B[r,e] = V0[e>>4,r]*V1[e&15,r]
// D = mfma(Btable_frag, W_frag): D[m=e_in_block, n=token], so each lane's 4
// acc regs are 4 CONSECUTIVE e for one token -> one global_store_dwordx4.
// No LDS, no barriers. Memory floor = the 105 MB f32 output (~17 us).

#define RANKK 32
#define EMB 128
#define WAVES_PER_BLOCK 4

typedef __attribute__((ext_vector_type(8))) short short8v;  // 8 bf16 = 4 VGPRs
typedef __attribute__((ext_vector_type(4))) float f32x4;

__device__ __forceinline__ short f2bf(float f) {
    union { __hip_bfloat16 h; short s; } u;
    u.h = __float2bfloat16(f);   // RNE
    return u.s;
}

__global__ __launch_bounds__(256) void cpemb_mfma(
    const int* __restrict__ x,
    const float* __restrict__ U0, const float* __restrict__ U1,
    const float* __restrict__ U2,
    const float* __restrict__ V0, const float* __restrict__ V1,
    float* __restrict__ out, int ntok)
{
    const int tid  = threadIdx.x;
    const int lane = tid & 63;
    const int gwave  = blockIdx.x * WAVES_PER_BLOCK + (tid >> 6);
    const int nwaves = gridDim.x * WAVES_PER_BLOCK;

    const int t_l = lane & 15;   // token-within-tile (B-operand n) == D col
    const int g   = lane >> 4;   // k-chunk group; also D row block (g*4+j)
    const int rb  = g * 8;       // this lane's rank base (k = rb..rb+7)

    // ---- loop-invariant table fragments (the MFMA *A* operand):
    // m = e_in_block = lane&15 -> V1 row = t_l; V0 row = eb (lane-uniform).
    float v1r[8];
    {
        const float4* p = (const float4*)(V1 + t_l * RANKK + rb);
        float4 lo = p[0], hi = p[1];
        v1r[0]=lo.x; v1r[1]=lo.y; v1r[2]=lo.z; v1r[3]=lo.w;
        v1r[4]=hi.x; v1r[5]=hi.y; v1r[6]=hi.z; v1r[7]=hi.w;
    }
    short8v bfrag[8];
    #pragma unroll
    for (int eb = 0; eb < 8; ++eb) {
        const float4* p = (const float4*)(V0 + eb * RANKK + rb);
        float4 lo = p[0], hi = p[1];
        float v0r[8] = {lo.x, lo.y, lo.z, lo.w, hi.x, hi.y, hi.z, hi.w};
        #pragma unroll
        for (int i = 0; i < 8; ++i)
            bfrag[eb][i] = f2bf(v0r[i] * v1r[i]);
    }

    const int ngroups = (ntok + 15) >> 4;   // 16 tokens per group
    for (int grp = gwave; grp < ngroups; grp += nwaves) {
        const int t0 = grp << 4;

        // ---- W-fragment (the MFMA *B* operand): token = t0 + t_l, k = rb..rb+7
        int tok = t0 + t_l;
        if (tok >= ntok) tok = ntok - 1;           // tail clamp (masked on store)
        const unsigned ui  = (unsigned)x[tok];
        const unsigned a   = ui / 5000u;
        const unsigned rem = ui - a * 5000u;
        const unsigned b   = rem / 50u;
        const unsigned c   = rem - b * 50u;

        const float4* p0 = (const float4*)(U0 + a * RANKK + rb);
        const float4* p1 = (const float4*)(U1 + b * RANKK + rb);
        const float4* p2 = (const float4*)(U2 + c * RANKK + rb);
        float4 a0 = p0[0], a1 = p0[1];
        float4 b0 = p1[0], b1 = p1[1];
        float4 c0 = p2[0], c1 = p2[1];
        float wv[8];
        wv[0]=a0.x*b0.x*c0.x; wv[1]=a0.y*b0.y*c0.y;
        wv[2]=a0.z*b0.z*c0.z; wv[3]=a0.w*b0.w*c0.w;
        wv[4]=a1.x*b1.x*c1.x; wv[5]=a1.y*b1.y*c1.y;
        wv[6]=a1.z*b1.z*c1.z; wv[7]=a1.w*b1.w*c1.w;
        short8v afrag;
        #pragma unroll
        for (int i = 0; i < 8; ++i) afrag[i] = f2bf(wv[i]);

        // ---- 8 MFMAs: D[m=e_in_block, n=token] = Btable . W
        // lane holds token = t0 + t_l, e = eb*16 + g*4 + j (j=0..3 contiguous)
        const bool ok = (t0 + t_l) < ntok;
        float* orow = out + (size_t)(t0 + t_l) * EMB + g * 4;
        #pragma unroll
        for (int eb = 0; eb < 8; ++eb) {
            f32x4 acc = {0.f, 0.f, 0.f, 0.f};
            acc = __builtin_amdgcn_mfma_f32_16x16x32_bf16(bfrag[eb], afrag, acc, 0, 0, 0);
            if (ok) {
                float4 v = make_float4(acc[0], acc[1], acc[2], acc[3]);
                *(float4*)(orow + eb * 16) = v;   // global_store_dwordx4
            }
        }
    }
}

extern "C" void kernel_launch(void* const* d_in, const int* in_sizes, int n_in,
                              void* d_out, int out_size, void* d_ws, size_t ws_size,
                              hipStream_t stream) {
    const int*   x  = (const int*)d_in[0];
    const float* U0 = (const float*)d_in[1];
    const float* U1 = (const float*)d_in[2];
    const float* U2 = (const float*)d_in[3];
    const float* V0 = (const float*)d_in[4];
    const float* V1 = (const float*)d_in[5];
    float* out = (float*)d_out;

    const int ntok = in_sizes[0];   // 204800
    const int blocks = 1024;        // 4 blocks/CU, 4096 waves, ~3.125 groups/wave

    cpemb_mfma<<<blocks, 256, 0, stream>>>(x, U0, U1, U2, V0, V1, out, ntok);
}